// Round 12
// baseline (4463.959 us; speedup 1.0000x reference)
//
#include <hip/hip_runtime.h>
#include <math.h>

#define B_ 64
#define S_ 512
#define I_ 300
#define H_ 512
#define T_ 25

typedef short bf16x8 __attribute__((ext_vector_type(8)));
typedef float f32x4  __attribute__((ext_vector_type(4)));
typedef int   s32x4  __attribute__((ext_vector_type(4)));

// Shared slot->k convention for MFMA fragments (A and B use the SAME map, so
// any bijection is self-consistent; verified numerically in rounds 6-11):
//   k = 16*(j>>2) + 4*((l>>4)&3) + (j&3)
__host__ __device__ __forceinline__ int kmap(int l, int j) {
    return 16 * (j >> 2) + 4 * ((l >> 4) & 3) + (j & 3);
}

// ---------------- workspace layout (float elements) ----------------
// x B-fragments: [s][dir][kh][nt][kt(5)][hilo][lane][8] shorts
static constexpr size_t SZ_XBF_S = (size_t)S_ * 2 * 2 * 4 * 5 * 2 * 64 * 8; // 41,943,040
static constexpr size_t OFS_XBF  = 0;
static constexpr size_t OFS_WHF  = OFS_XBF + SZ_XBF_S / 2;       // h A-frags (shorts)
static constexpr size_t SZ_WHF_S = (size_t)2 * 128 * 2 * 8 * 2 * 64 * 8;  // 4,194,304
static constexpr size_t OFS_WXF  = OFS_WHF + SZ_WHF_S / 2;       // x A-frags (shorts)
static constexpr size_t SZ_WXF_S = (size_t)2 * 128 * 2 * 5 * 2 * 64 * 8;  // 2,621,440
static constexpr size_t OFS_YF   = OFS_WXF + SZ_WXF_S / 2;
static constexpr size_t SZ_Y     = (size_t)S_ * H_ * B_;         // 16,777,216
static constexpr size_t OFS_YB   = OFS_YF + SZ_Y;
static constexpr size_t SZ_L     = (size_t)B_ * S_ * T_;         // 819,200
static constexpr size_t OFS_L1   = OFS_YB + SZ_Y;
static constexpr size_t OFS_L2   = OFS_L1 + SZ_L;
static constexpr size_t OFS_LEN  = OFS_L2 + SZ_L;   // int32[64]
static constexpr size_t OFS_LLH  = OFS_LEN + 64;    // float[64]
static constexpr size_t OFS_FLG  = OFS_LLH + 64;    // int32: [dir][ug] 64B lines,
                                                    // words 0..3 = finalizer wave wq

// output layout (float elements in d_out)
static constexpr size_t OFF_LOGITS = 1;
static constexpr size_t OFF_TAGS   = 1 + SZ_L;
static constexpr size_t OFF_MASK   = OFF_TAGS + (size_t)B_ * S_;

// ---------------- small utility kernels ----------------
__global__ void k_lengths(const int* __restrict__ am, int* __restrict__ len) {
    int b = threadIdx.x;
    int sum = 0;
    for (int s = 0; s < S_; ++s) sum += am[b * S_ + s];
    len[b] = sum;
}

__global__ void k_zero(float* __restrict__ p, int n) {
    int idx = blockIdx.x * 256 + threadIdx.x;
    if (idx < n) p[idx] = 0.f;
}

// Whh -> per-(dir,ug) A-fragment streams, split bf16 hi/lo (round-6 verified).
// short idx = [((((dir*128+ug)*2+kh)*8 + kt)*2 + hilo)*64 + lane]*8 + j
__global__ void k_prep_hfrag(const float* __restrict__ whhf,
                             const float* __restrict__ whhb,
                             short* __restrict__ hf) {
    for (size_t idx = (size_t)blockIdx.x * 256 + threadIdx.x; idx < SZ_WHF_S;
         idx += (size_t)gridDim.x * 256) {
        int j = (int)(idx & 7); size_t t = idx >> 3;
        int l = (int)(t & 63); t >>= 6;
        int hilo = (int)(t & 1); t >>= 1;
        int kt = (int)(t & 7); t >>= 3;
        int kh = (int)(t & 1); t >>= 1;
        int ug = (int)(t & 127); t >>= 7;
        int dir = (int)t;
        int m = l & 15;
        int row = (m & 3) * H_ + ug * 4 + (m >> 2);   // g*H + u
        int k = kh * 256 + kt * 32 + kmap(l, j);
        float w = (dir ? whhb : whhf)[(size_t)row * H_ + k];
        unsigned u32 = __float_as_uint(w);
        float hi_f = __uint_as_float(u32 & 0xffff0000u);
        hf[idx] = hilo ? (short)(__float_as_uint(w - hi_f) >> 16)
                       : (short)(u32 >> 16);
    }
}

// W_ih -> x A-fragments (K padded 300->320 with zeros), round-6 verified.
__global__ void k_prep_xfrag(const float* __restrict__ wihf,
                             const float* __restrict__ wihb,
                             short* __restrict__ xf) {
    for (size_t idx = (size_t)blockIdx.x * 256 + threadIdx.x; idx < SZ_WXF_S;
         idx += (size_t)gridDim.x * 256) {
        int j = (int)(idx & 7); size_t t = idx >> 3;
        int l = (int)(t & 63); t >>= 6;
        int hilo = (int)(t & 1); t >>= 1;
        int kt = (int)(t % 5); t /= 5;
        int kh = (int)(t & 1); t >>= 1;
        int ug = (int)(t & 127); t >>= 7;
        int dir = (int)t;
        int m = l & 15;
        int row = (m & 3) * H_ + ug * 4 + (m >> 2);
        int k = kh * 160 + kt * 32 + kmap(l, j);
        float w = 0.f;
        if (k < I_) w = (dir ? wihb : wihf)[(size_t)row * I_ + k];
        unsigned u32 = __float_as_uint(w);
        float hi_f = __uint_as_float(u32 & 0xffff0000u);
        xf[idx] = hilo ? (short)(__float_as_uint(w - hi_f) >> 16)
                       : (short)(u32 >> 16);
    }
}

// x -> B-fragments, precomputed per (s, dir, kh, nt, kt, hilo) (round-7
// verified): coalesced dwordx4 consumer loads, shared L2-wide.
// short idx = [(((((s*2+dir)*2+kh)*4+nt)*5 + kt)*2 + hilo)*64 + lane]*8 + j
__global__ void k_prep_xb(const float* __restrict__ x, const int* __restrict__ len,
                          short* __restrict__ xb) {
    for (size_t idx = (size_t)blockIdx.x * 256 + threadIdx.x; idx < SZ_XBF_S;
         idx += (size_t)gridDim.x * 256) {
        int j = (int)(idx & 7); size_t t = idx >> 3;
        int l = (int)(t & 63); t >>= 6;
        int hilo = (int)(t & 1); t >>= 1;
        int kt = (int)(t % 5); t /= 5;
        int nt = (int)(t & 3); t >>= 2;
        int kh = (int)(t & 1); t >>= 1;
        int dir = (int)(t & 1); t >>= 1;
        int s = (int)t;
        int b = nt * 16 + (l & 15);
        int k = kh * 160 + kt * 32 + kmap(l, j);
        float v = 0.f;
        if (k < I_) {
            int src = s;
            if (dir) { int L = len[b]; src = (s < L) ? (L - 1 - s) : s; }
            v = x[((size_t)b * S_ + src) * I_ + k];
        }
        unsigned u32 = __float_as_uint(v);
        float hi_f = __uint_as_float(u32 & 0xffff0000u);
        xb[idx] = hilo ? (short)(__float_as_uint(v - hi_f) >> 16)
                       : (short)(u32 >> 16);
    }
}

// ---- persistent BiLSTM scan: round-7 base, single barrier per step ----
// 256 blocks x 512 threads (cooperative; NO grid.sync). Block = (dir, ug);
// wave wq = (nt = wq>>1: 16 b-cols; kh = wq&1: K-half). Weights LDS-resident
// (round-7 proven). fp32 y [s][u][b] exchange: producer stores COALESCED
// (4 lines/wave — round-11 lesson: producer-side coalescing dominates;
// scattered producer stores caused 16x write amplification on the drain path).
// SINGLE structural delta vs the verified 2.43ms round-7 kernel:
//   second block barrier removed. parts is step-parity double-buffered;
//   each finalizer wave (wq<4) drains its OWN coalesced y-quarter
//   (vmcnt(0)) and writes its OWN flag word (4 words per (dir,ug) 64B
//   line). Consumers poll one device-scope dwordx4 + min4. Producer waves
//   (wq>=4) run ahead into step s+1's x-phase while finalizers drain.
// Safety: the one barrier/step totally orders read-parts(s) < barrier(s+1)
// < write-parts(s+2) within a block; parity buffers are disjoint.
// Spins use s_sleep(1) (round-9 lesson: hot-spin starves LDS).
__global__ __launch_bounds__(512, 2) void k_scan(
    const short* __restrict__ whf, const short* __restrict__ wxf,
    const short* __restrict__ xbf,
    float* yf, float* ybr,
    const float* __restrict__ bf, const float* __restrict__ bb,
    const int* __restrict__ len, int* __restrict__ flg)
{
    __shared__ bf16x8 hA[16 * 2 * 64];   // 32 KB  [kt2][hilo][lane], kt2=kh*8+kt
    __shared__ bf16x8 xA[10 * 2 * 64];   // 20 KB  [kt2][hilo][lane], kt2=kh*5+kt
    __shared__ float parts[2 * 32 * 66]; // 16.5 KB, [par][kh*16+m][bcol] stride-66
    const int dir = blockIdx.x >> 7;
    const int ug  = blockIdx.x & 127;
    const int tid = threadIdx.x;
    const int lane = tid & 63;
    const int wq = __builtin_amdgcn_readfirstlane(tid >> 6);  // 0..7
    const int nt = wq >> 1, kh = wq & 1;
    const int bcol = (nt << 4) + (lane & 15);

    // ---- stage A-fragments into LDS, once ----
    {
        const bf16x8* whp = (const bf16x8*)whf + (size_t)(dir * 128 + ug) * 2048;
        for (int i = tid; i < 2048; i += 512) hA[i] = whp[i];
        const bf16x8* wxp = (const bf16x8*)wxf + (size_t)(dir * 128 + ug) * 1280;
        for (int i = tid; i < 1280; i += 512) xA[i] = wxp[i];
    }

    float* ybase = dir ? ybr : yf;
    int* const flgline = flg + ((size_t)(dir * 128 + ug) << 4);   // own 64B line
    const int* const fpp = flg + ((size_t)(dir * 128 + (kh << 6) + lane) << 4);

    // finalizer (waves 0..3 = uu) persistent state
    const int uF = (ug << 2) + wq;      // valid when wq<4
    float c_reg = 0.f;
    float bi0 = 0.f, bi1 = 0.f, bi2 = 0.f, bi3 = 0.f;
    if (wq < 4) {
        const float* bias = dir ? bb : bf;
        bi0 = bias[uF]; bi1 = bias[H_ + uF];
        bi2 = bias[2 * H_ + uF]; bi3 = bias[3 * H_ + uF];
    }
    const int Lb = len[lane];

    int ko[8];
#pragma unroll
    for (int j = 0; j < 8; ++j) ko[j] = kmap(lane, j);

    __syncthreads();   // LDS A-frags ready

    for (int s = 0; s < S_; ++s) {
        f32x4 d0 = {0.f, 0.f, 0.f, 0.f};
        f32x4 d1 = {0.f, 0.f, 0.f, 0.f};

        // ---- x-phase for this K-half (h-independent, pre-wait) ----
        {
            const bf16x8* xb = (const bf16x8*)xbf +
                ((((size_t)(s * 2 + dir) * 2 + kh) * 4 + nt) * 5) * 2 * 64;
#pragma unroll
            for (int kt = 0; kt < 5; ++kt) {
                bf16x8 b_h = xb[(kt * 2 + 0) * 64 + lane];
                bf16x8 b_l = xb[(kt * 2 + 1) * 64 + lane];
                bf16x8 a_h = xA[((kh * 5 + kt) * 2 + 0) * 64 + lane];
                bf16x8 a_l = xA[((kh * 5 + kt) * 2 + 1) * 64 + lane];
                d0 = __builtin_amdgcn_mfma_f32_16x16x32_bf16(a_h, b_h, d0, 0, 0, 0);
                d1 = __builtin_amdgcn_mfma_f32_16x16x32_bf16(a_h, b_l, d1, 0, 0, 0);
                d0 = __builtin_amdgcn_mfma_f32_16x16x32_bf16(a_l, b_h, d0, 0, 0, 0);
            }
        }

        // ---- wait: 64 producer lines of this K-half, 4 flag words each ----
        if (s) {
            for (;;) {
                s32x4 v;
                asm volatile("global_load_dwordx4 %0, %1, off sc0 sc1\n\t"
                             "s_waitcnt vmcnt(0)"
                             : "=&v"(v) : "v"(fpp) : "memory");
                int mna = v[0] < v[1] ? v[0] : v[1];
                int mnb = v[2] < v[3] ? v[2] : v[3];
                int mn = mna < mnb ? mna : mnb;
                if (__all(mn >= s)) break;
                __builtin_amdgcn_s_sleep(1);
            }
        }
        asm volatile("" ::: "memory");

        // ---- h-phase: plain cacheable loads of y[s-1] (L2-shared per XCD) ----
        if (s) {
            const float* hprev = ybase + ((size_t)(s - 1) << 15);   // H_*B_
#pragma unroll
            for (int kt = 0; kt < 8; ++kt) {
                const int k0 = (kh << 8) + kt * 32;
                float hv[8];
#pragma unroll
                for (int j = 0; j < 8; ++j)
                    hv[j] = hprev[((size_t)(k0 + ko[j]) << 6) + bcol];
                bf16x8 b_h, b_l;
#pragma unroll
                for (int j = 0; j < 8; ++j) {
                    unsigned u32 = __float_as_uint(hv[j]);
                    b_h[j] = (short)(u32 >> 16);
                    float hi_f = __uint_as_float(u32 & 0xffff0000u);
                    b_l[j] = (short)(__float_as_uint(hv[j] - hi_f) >> 16);
                }
                bf16x8 a_h = hA[((kh * 8 + kt) * 2 + 0) * 64 + lane];
                bf16x8 a_l = hA[((kh * 8 + kt) * 2 + 1) * 64 + lane];
                d0 = __builtin_amdgcn_mfma_f32_16x16x32_bf16(a_h, b_h, d0, 0, 0, 0);
                d1 = __builtin_amdgcn_mfma_f32_16x16x32_bf16(a_h, b_l, d1, 0, 0, 0);
                d0 = __builtin_amdgcn_mfma_f32_16x16x32_bf16(a_l, b_h, d0, 0, 0, 0);
            }
        }

        // ---- dump partial into parity buffer, the ONE barrier ----
        const int par = s & 1;
        {
            const int m0 = (lane >> 4) << 2;
#pragma unroll
            for (int r = 0; r < 4; ++r)
                parts[((par << 5) + (kh << 4) + m0 + r) * 66 + bcol] = d0[r] + d1[r];
        }
        __syncthreads();

        if (wq < 4) {
            const int rb = wq << 2;   // m = uu*4 + g, uu = wq
            const float* pp = parts + (size_t)(par << 5) * 66;
            float g0 = bi0 + pp[(rb + 0) * 66 + lane] + pp[(16 + rb + 0) * 66 + lane];
            float g1 = bi1 + pp[(rb + 1) * 66 + lane] + pp[(16 + rb + 1) * 66 + lane];
            float g2 = bi2 + pp[(rb + 2) * 66 + lane] + pp[(16 + rb + 2) * 66 + lane];
            float g3 = bi3 + pp[(rb + 3) * 66 + lane] + pp[(16 + rb + 3) * 66 + lane];
            float ii = 1.f / (1.f + expf(-g0));
            float ff = 1.f / (1.f + expf(-g1));
            float gg = tanhf(g2);
            float oo = 1.f / (1.f + expf(-g3));
            float cn2 = ff * c_reg + ii * gg;
            float hn = oo * tanhf(cn2);
            c_reg = cn2;                       // post-length state is don't-care
            float yv = (s < Lb) ? hn : 0.f;
            // coalesced device-scope y store (4 lines per wave)
            __hip_atomic_store(&ybase[((size_t)(s * H_ + uF) << 6) + lane], yv,
                               __ATOMIC_RELAXED, __HIP_MEMORY_SCOPE_AGENT);
            // drain OWN quarter, then OWN flag word (no 2nd barrier)
            asm volatile("s_waitcnt vmcnt(0)" ::: "memory");
            if (lane == 0)
                __hip_atomic_store(flgline + wq, s + 1, __ATOMIC_RELAXED,
                                   __HIP_MEMORY_SCOPE_AGENT);
        }
    }
}

// ---------------- logits / CRF epilogue (round-7 verified) ----------------
__global__ __launch_bounds__(256) void k_logits(const float* __restrict__ yf,
                                                const float* __restrict__ ybr,
                                                const float* __restrict__ wc,
                                                const float* __restrict__ bcv,
                                                float* __restrict__ L1,
                                                float* __restrict__ L2p) {
    __shared__ float smem[T_ * H_];
    int part = blockIdx.x >> 9;
    int s = blockIdx.x & 511;
    int tid = threadIdx.x;
    const float* y = part ? ybr : yf;
    float* Ldst = part ? L2p : L1;
    for (int idx = tid; idx < T_ * H_; idx += 256) {
        int t = idx >> 9;
        int h = idx & 511;
        smem[idx] = wc[(size_t)t * 1024 + part * 512 + h];
    }
    __syncthreads();
    int q = tid >> 6, b = tid & 63;
    float acc[T_];
#pragma unroll
    for (int t = 0; t < T_; ++t) acc[t] = 0.f;
    const float* yrow = y + (size_t)s * H_ * B_ + b;
    for (int h = q * 128; h < q * 128 + 128; ++h) {
        float a = yrow[(size_t)h * B_];
#pragma unroll
        for (int t = 0; t < T_; ++t) acc[t] += a * smem[t * H_ + h];
    }
    __syncthreads();
    float* pl = smem;
#pragma unroll
    for (int t = 0; t < T_; ++t) pl[(q * 64 + b) * 26 + t] = acc[t];
    __syncthreads();
    for (int idx = tid; idx < B_ * T_; idx += 256) {
        int bb2 = idx / T_;
        int t = idx - bb2 * T_;
        float v = pl[(0 * 64 + bb2) * 26 + t] + pl[(1 * 64 + bb2) * 26 + t] +
                  pl[(2 * 64 + bb2) * 26 + t] + pl[(3 * 64 + bb2) * 26 + t];
        if (!part) v += bcv[t];
        Ldst[((size_t)bb2 * S_ + s) * T_ + t] = v;
    }
}

__global__ void k_combine(const float* __restrict__ L1, const float* __restrict__ L2p,
                          const int* __restrict__ len, float* __restrict__ outlog) {
    int id = blockIdx.x * 256 + threadIdx.x;  // 32768 = B*S
    int b = id >> 9;
    int s = id & 511;
    int L = len[b];
    int sr = (s < L) ? (L - 1 - s) : s;
    const float* p1 = L1 + ((size_t)b * S_ + s) * T_;
    const float* p2 = L2p + ((size_t)b * S_ + sr) * T_;
    float* o = outlog + ((size_t)b * S_ + s) * T_;
#pragma unroll
    for (int t = 0; t < T_; ++t) o[t] = p1[t] + p2[t];
}

__global__ __launch_bounds__(64) void k_crf_nll(const float* __restrict__ em,
                                                const int* __restrict__ labels,
                                                const int* __restrict__ len,
                                                const float* __restrict__ cs,
                                                const float* __restrict__ ce,
                                                const float* __restrict__ ctr,
                                                float* __restrict__ llh) {
    int b = blockIdx.x, tid = threadIdx.x;
    __shared__ float tr[T_ * T_];
    __shared__ float sa[T_], sb[T_];
    for (int idx = tid; idx < T_ * T_; idx += 64) tr[idx] = ctr[idx];
    const float* e = em + (size_t)b * S_ * T_;
    int L = len[b];
    if (tid < T_) sa[tid] = cs[tid] + e[tid];
    __syncthreads();
    float* cur = sa;
    float* nx = sb;
    for (int t = 1; t < L; ++t) {
        if (tid < T_) {
            float m = -1e30f;
            for (int i = 0; i < T_; ++i) m = fmaxf(m, cur[i] + tr[i * T_ + tid]);
            float ssum = 0.f;
            for (int i = 0; i < T_; ++i) ssum += expf(cur[i] + tr[i * T_ + tid] - m);
            nx[tid] = m + logf(ssum) + e[(size_t)t * T_ + tid];
        }
        __syncthreads();
        float* tmp = cur; cur = nx; nx = tmp;
    }
    float part = 0.f;
    for (int t = tid; t < S_; t += 64) {
        if (t >= 1 && t < L) {
            int lp = labels[b * S_ + t - 1];
            int lc = labels[b * S_ + t];
            part += tr[lp * T_ + lc] + e[(size_t)t * T_ + lc];
        }
    }
    for (int off = 32; off; off >>= 1) part += __shfl_down(part, off, 64);
    if (tid == 0) {
        float m = -1e30f;
        for (int j = 0; j < T_; ++j) m = fmaxf(m, cur[j] + ce[j]);
        float ssum = 0.f;
        for (int j = 0; j < T_; ++j) ssum += expf(cur[j] + ce[j] - m);
        float denom = m + logf(ssum);
        int l0 = labels[b * S_];
        int lL = labels[b * S_ + L - 1];
        float num = cs[l0] + e[l0] + part + ce[lL];
        llh[b] = num - denom;
    }
}

__global__ void k_loss(const float* __restrict__ llh, const int* __restrict__ len,
                       float* __restrict__ out0) {
    int tid = threadIdx.x;
    float v = llh[tid];
    float n = (float)len[tid];
    for (int off = 32; off; off >>= 1) {
        v += __shfl_down(v, off, 64);
        n += __shfl_down(n, off, 64);
    }
    if (tid == 0) out0[0] = -(v / n);
}

__global__ __launch_bounds__(64) void k_viterbi(const float* __restrict__ em,
                                                const int* __restrict__ len,
                                                const float* __restrict__ cs,
                                                const float* __restrict__ ce,
                                                const float* __restrict__ ctr,
                                                float* __restrict__ otags,
                                                float* __restrict__ omask) {
    int b = blockIdx.x, tid = threadIdx.x;
    __shared__ float tr[T_ * T_];
    __shared__ float sa[T_], sb[T_];
    __shared__ unsigned char hist[(S_ - 1) * T_];
    __shared__ unsigned char tg[S_];
    for (int idx = tid; idx < T_ * T_; idx += 64) tr[idx] = ctr[idx];
    const float* e = em + (size_t)b * S_ * T_;
    int L = len[b];
    if (tid < T_) sa[tid] = cs[tid] + e[tid];
    __syncthreads();
    float* cur = sa;
    float* nx = sb;
    for (int t = 1; t < L; ++t) {
        if (tid < T_) {
            float best = -1e30f;
            int bi = 0;
            for (int i = 0; i < T_; ++i) {
                float v = cur[i] + tr[i * T_ + tid];
                if (v > best) { best = v; bi = i; }
            }
            nx[tid] = best + e[(size_t)t * T_ + tid];
            hist[(t - 1) * T_ + tid] = (unsigned char)bi;
        }
        __syncthreads();
        float* tmp = cur; cur = nx; nx = tmp;
    }
    if (tid == 0) {
        float best = -1e30f;
        int bt = 0;
        for (int j = 0; j < T_; ++j) {
            float v = cur[j] + ce[j];
            if (v > best) { best = v; bt = j; }
        }
        tg[S_ - 1] = (unsigned char)bt;
        for (int t = S_ - 2; t >= 0; --t) {
            if (t + 1 < L) bt = hist[t * T_ + bt];
            tg[t] = (unsigned char)bt;
        }
    }
    __syncthreads();
    for (int idx = tid; idx < S_; idx += 64) {
        otags[(size_t)b * S_ + idx] = (float)tg[idx];
        omask[(size_t)b * S_ + idx] = (idx < L) ? 1.f : 0.f;
    }
}

// ---------------- host launch ----------------
extern "C" void kernel_launch(void* const* d_in, const int* in_sizes, int n_in,
                              void* d_out, int out_size, void* d_ws, size_t ws_size,
                              hipStream_t stream) {
    const float* x    = (const float*)d_in[0];
    const float* wihf = (const float*)d_in[1];
    const float* whhf = (const float*)d_in[2];
    const float* bf   = (const float*)d_in[3];
    const float* wihb = (const float*)d_in[4];
    const float* whhb = (const float*)d_in[5];
    const float* bb   = (const float*)d_in[6];
    const float* wc   = (const float*)d_in[7];
    const float* bc   = (const float*)d_in[8];
    const float* cs   = (const float*)d_in[9];
    const float* ce   = (const float*)d_in[10];
    const float* ctr  = (const float*)d_in[11];
    const int* am     = (const int*)d_in[12];
    const int* labels = (const int*)d_in[13];

    float* ws   = (float*)d_ws;
    short* xbfr = (short*)(ws + OFS_XBF);
    short* whfr = (short*)(ws + OFS_WHF);
    short* wxfr = (short*)(ws + OFS_WXF);
    float* yf   = ws + OFS_YF;
    float* ybr  = ws + OFS_YB;
    float* L1p  = ws + OFS_L1;
    float* L2p  = ws + OFS_L2;
    int*   lenp = (int*)(ws + OFS_LEN);
    float* llhp = ws + OFS_LLH;
    int*   flgp = (int*)(ws + OFS_FLG);
    float* out  = (float*)d_out;

    k_lengths<<<1, 64, 0, stream>>>(am, lenp);
    k_prep_hfrag<<<2048, 256, 0, stream>>>(whhf, whhb, whfr);
    k_prep_xfrag<<<2048, 256, 0, stream>>>(wihf, wihb, wxfr);
    k_prep_xb<<<8192, 256, 0, stream>>>(x, lenp, xbfr);
    k_zero<<<16, 256, 0, stream>>>(ws + OFS_FLG, 2 * 128 * 16);  // flag lines

    {
        void* kargs[] = {
            (void*)&whfr, (void*)&wxfr, (void*)&xbfr,
            (void*)&yf, (void*)&ybr,
            (void*)&bf, (void*)&bb,
            (void*)&lenp, (void*)&flgp
        };
        hipLaunchCooperativeKernel((const void*)k_scan,
                                   dim3(256), dim3(512), kargs, 0, stream);
    }

    k_logits<<<1024, 256, 0, stream>>>(yf, ybr, wc, bc, L1p, L2p);
    k_combine<<<128, 256, 0, stream>>>(L1p, L2p, lenp, out + OFF_LOGITS);
    k_crf_nll<<<64, 64, 0, stream>>>(out + OFF_LOGITS, labels, lenp, cs, ce, ctr, llhp);
    k_loss<<<1, 64, 0, stream>>>(llhp, lenp, out);
    k_viterbi<<<64, 64, 0, stream>>>(out + OFF_LOGITS, lenp, cs, ce, ctr,
                                     out + OFF_TAGS, out + OFF_MASK);
}

// Round 13
// 3721.414 us; speedup vs baseline: 1.1995x; 1.1995x over previous
//
#include <hip/hip_runtime.h>
#include <math.h>

#define B_ 64
#define S_ 512
#define I_ 300
#define H_ 512
#define T_ 25

typedef short bf16x8 __attribute__((ext_vector_type(8)));
typedef float f32x4  __attribute__((ext_vector_type(4)));

// Shared slot->k convention for MFMA fragments (A and B use the SAME map, so
// any bijection is self-consistent; verified numerically in rounds 6-12):
//   k = 16*(j>>2) + 4*((l>>4)&3) + (j&3)
__host__ __device__ __forceinline__ int kmap(int l, int j) {
    return 16 * (j >> 2) + 4 * ((l >> 4) & 3) + (j & 3);
}

// ---------------- workspace layout (float elements) ----------------
// x B-fragments: [s][dir][kh][nt][kt(5)][hilo][lane][8] shorts
static constexpr size_t SZ_XBF_S = (size_t)S_ * 2 * 2 * 4 * 5 * 2 * 64 * 8; // 41,943,040
static constexpr size_t OFS_XBF  = 0;
static constexpr size_t OFS_WHF  = OFS_XBF + SZ_XBF_S / 2;       // h A-frags (shorts)
static constexpr size_t SZ_WHF_S = (size_t)2 * 128 * 2 * 8 * 2 * 64 * 8;  // 4,194,304
static constexpr size_t OFS_WXF  = OFS_WHF + SZ_WHF_S / 2;       // x A-frags (shorts)
static constexpr size_t SZ_WXF_S = (size_t)2 * 128 * 2 * 5 * 2 * 64 * 8;  // 2,621,440
static constexpr size_t OFS_YF   = OFS_WXF + SZ_WXF_S / 2;
static constexpr size_t SZ_Y     = (size_t)S_ * H_ * B_;         // 16,777,216
static constexpr size_t OFS_YB   = OFS_YF + SZ_Y;
static constexpr size_t SZ_L     = (size_t)B_ * S_ * T_;         // 819,200
static constexpr size_t OFS_L1   = OFS_YB + SZ_Y;
static constexpr size_t OFS_L2   = OFS_L1 + SZ_L;
static constexpr size_t OFS_LEN  = OFS_L2 + SZ_L;   // int32[64]
static constexpr size_t OFS_LLH  = OFS_LEN + 64;    // float[64]
static constexpr size_t OFS_FLG  = OFS_LLH + 64;    // int32[2*128*16] per-block flags,
                                                    // one 64B line each

// output layout (float elements in d_out)
static constexpr size_t OFF_LOGITS = 1;
static constexpr size_t OFF_TAGS   = 1 + SZ_L;
static constexpr size_t OFF_MASK   = OFF_TAGS + (size_t)B_ * S_;

// ---------------- small utility kernels ----------------
__global__ void k_lengths(const int* __restrict__ am, int* __restrict__ len) {
    int b = threadIdx.x;
    int sum = 0;
    for (int s = 0; s < S_; ++s) sum += am[b * S_ + s];
    len[b] = sum;
}

__global__ void k_zero(float* __restrict__ p, int n) {
    int idx = blockIdx.x * 256 + threadIdx.x;
    if (idx < n) p[idx] = 0.f;
}

// Whh -> per-(dir,ug) A-fragment streams, split bf16 hi/lo (round-6 verified).
// short idx = [((((dir*128+ug)*2+kh)*8 + kt)*2 + hilo)*64 + lane]*8 + j
__global__ void k_prep_hfrag(const float* __restrict__ whhf,
                             const float* __restrict__ whhb,
                             short* __restrict__ hf) {
    for (size_t idx = (size_t)blockIdx.x * 256 + threadIdx.x; idx < SZ_WHF_S;
         idx += (size_t)gridDim.x * 256) {
        int j = (int)(idx & 7); size_t t = idx >> 3;
        int l = (int)(t & 63); t >>= 6;
        int hilo = (int)(t & 1); t >>= 1;
        int kt = (int)(t & 7); t >>= 3;
        int kh = (int)(t & 1); t >>= 1;
        int ug = (int)(t & 127); t >>= 7;
        int dir = (int)t;
        int m = l & 15;
        int row = (m & 3) * H_ + ug * 4 + (m >> 2);   // g*H + u
        int k = kh * 256 + kt * 32 + kmap(l, j);
        float w = (dir ? whhb : whhf)[(size_t)row * H_ + k];
        unsigned u32 = __float_as_uint(w);
        float hi_f = __uint_as_float(u32 & 0xffff0000u);
        hf[idx] = hilo ? (short)(__float_as_uint(w - hi_f) >> 16)
                       : (short)(u32 >> 16);
    }
}

// W_ih -> x A-fragments (K padded 300->320 with zeros), round-6 verified.
__global__ void k_prep_xfrag(const float* __restrict__ wihf,
                             const float* __restrict__ wihb,
                             short* __restrict__ xf) {
    for (size_t idx = (size_t)blockIdx.x * 256 + threadIdx.x; idx < SZ_WXF_S;
         idx += (size_t)gridDim.x * 256) {
        int j = (int)(idx & 7); size_t t = idx >> 3;
        int l = (int)(t & 63); t >>= 6;
        int hilo = (int)(t & 1); t >>= 1;
        int kt = (int)(t % 5); t /= 5;
        int kh = (int)(t & 1); t >>= 1;
        int ug = (int)(t & 127); t >>= 7;
        int dir = (int)t;
        int m = l & 15;
        int row = (m & 3) * H_ + ug * 4 + (m >> 2);
        int k = kh * 160 + kt * 32 + kmap(l, j);
        float w = 0.f;
        if (k < I_) w = (dir ? wihb : wihf)[(size_t)row * I_ + k];
        unsigned u32 = __float_as_uint(w);
        float hi_f = __uint_as_float(u32 & 0xffff0000u);
        xf[idx] = hilo ? (short)(__float_as_uint(w - hi_f) >> 16)
                       : (short)(u32 >> 16);
    }
}

// x -> B-fragments, precomputed per (s, dir, kh, nt, kt, hilo): kills the
// scan's per-step scatter loads + split VALU for x; consumer loads are
// contiguous dwordx4 shared by all 128 ug-blocks of a dir (L2-friendly).
// short idx = [(((((s*2+dir)*2+kh)*4+nt)*5 + kt)*2 + hilo)*64 + lane]*8 + j
__global__ void k_prep_xb(const float* __restrict__ x, const int* __restrict__ len,
                          short* __restrict__ xb) {
    for (size_t idx = (size_t)blockIdx.x * 256 + threadIdx.x; idx < SZ_XBF_S;
         idx += (size_t)gridDim.x * 256) {
        int j = (int)(idx & 7); size_t t = idx >> 3;
        int l = (int)(t & 63); t >>= 6;
        int hilo = (int)(t & 1); t >>= 1;
        int kt = (int)(t % 5); t /= 5;
        int nt = (int)(t & 3); t >>= 2;
        int kh = (int)(t & 1); t >>= 1;
        int dir = (int)(t & 1); t >>= 1;
        int s = (int)t;
        int b = nt * 16 + (l & 15);
        int k = kh * 160 + kt * 32 + kmap(l, j);
        float v = 0.f;
        if (k < I_) {
            int src = s;
            if (dir) { int L = len[b]; src = (s < L) ? (L - 1 - s) : s; }
            v = x[((size_t)b * S_ + src) * I_ + k];
        }
        unsigned u32 = __float_as_uint(v);
        float hi_f = __uint_as_float(u32 & 0xffff0000u);
        xb[idx] = hilo ? (short)(__float_as_uint(v - hi_f) >> 16)
                       : (short)(u32 >> 16);
    }
}

// ---------------- persistent BiLSTM scan: split-bf16 MFMA, LDS weights ----
// 256 blocks x 512 threads (cooperative for co-residency; NO grid.sync).
// Block = (dir, ug) owns units u=ug*4..+3 (one 16-row M-tile in permuted
// row space r' = uu*4+g). Wave wq = (nt = wq>>1: b-cols; kh = wq&1: K-half).
// WEIGHTS: A-fragments staged ONCE into LDS (frags are nt-independent ->
// 32 KB h + 20 KB x per block) — round-7 proven: removes the 16.4 GB/dispatch
// fabric re-streaming that pinned the register-resident variant at 9.5 ms.
// x-phase: precomputed B-frags (coalesced dwordx4) + 15 MFMAs, pre-wait.
// h-phase: scattered y[s-1] loads + split + 24 MFMAs, post-wait.
// Sync: per-block flag lines, all-64-lane poll, two barriers per step —
// the VERIFIED optimum; 5 protocol variants (r8/r9/r11/r12) all regressed.
__global__ __launch_bounds__(512, 2) void k_scan(
    const short* __restrict__ whf, const short* __restrict__ wxf,
    const short* __restrict__ xbf,
    float* yf, float* ybr,
    const float* __restrict__ bf, const float* __restrict__ bb,
    const int* __restrict__ len, int* __restrict__ flg)
{
    __shared__ bf16x8 hA[2 * 8 * 2 * 64];   // 32 KB  [kh][kt][hilo][lane]
    __shared__ bf16x8 xA[2 * 5 * 2 * 64];   // 20 KB  [kh][kt][hilo][lane]
    __shared__ float parts[32 * 66];        // 8.25 KB, stride-66 (bank-safe)
    const int dir = blockIdx.x >> 7;
    const int ug  = blockIdx.x & 127;
    const int tid = threadIdx.x;
    const int lane = tid & 63;
    const int wq = __builtin_amdgcn_readfirstlane(tid >> 6);  // 0..7
    const int nt = wq >> 1, kh = wq & 1;
    const int bcol = (nt << 4) + (lane & 15);

    // ---- stage A-fragments into LDS, once ----
    {
        const bf16x8* whp = (const bf16x8*)whf + (size_t)(dir * 128 + ug) * 2048;
        for (int i = tid; i < 2048; i += 512) hA[i] = whp[i];
        const bf16x8* wxp = (const bf16x8*)wxf + (size_t)(dir * 128 + ug) * 1280;
        for (int i = tid; i < 1280; i += 512) xA[i] = wxp[i];
    }

    float* ybase = dir ? ybr : yf;
    int* const myflag = flg + ((size_t)(dir * 128 + ug) << 4);
    // wave kh consumes u in [kh*256, kh*256+256) -> producers ug' = kh*64+lane
    const int* const fp = flg + ((size_t)(dir * 128 + kh * 64 + lane) << 4);

    // finalizer (waves 0..3 = uu) persistent state
    const int uF = (ug << 2) + wq;
    float c_reg = 0.f;
    float bi0 = 0.f, bi1 = 0.f, bi2 = 0.f, bi3 = 0.f;
    if (wq < 4) {
        const float* bias = dir ? bb : bf;
        bi0 = bias[uF]; bi1 = bias[H_ + uF];
        bi2 = bias[2 * H_ + uF]; bi3 = bias[3 * H_ + uF];
    }
    const int Lb = len[lane];

    int ko[8];
#pragma unroll
    for (int j = 0; j < 8; ++j) ko[j] = kmap(lane, j);

    __syncthreads();   // LDS A-frags ready

    for (int s = 0; s < S_; ++s) {
        f32x4 d = {0.f, 0.f, 0.f, 0.f};

        // ---- x-phase (h-independent, pre-wait): coalesced frag loads ----
        {
            const bf16x8* xb = (const bf16x8*)xbf +
                ((((size_t)(s * 2 + dir) * 2 + kh) * 4 + nt) * 5) * 2 * 64;
#pragma unroll
            for (int kt = 0; kt < 5; ++kt) {
                bf16x8 b_h = xb[(kt * 2 + 0) * 64 + lane];
                bf16x8 b_l = xb[(kt * 2 + 1) * 64 + lane];
                bf16x8 a_h = xA[((kh * 5 + kt) * 2 + 0) * 64 + lane];
                bf16x8 a_l = xA[((kh * 5 + kt) * 2 + 1) * 64 + lane];
                d = __builtin_amdgcn_mfma_f32_16x16x32_bf16(a_h, b_h, d, 0, 0, 0);
                d = __builtin_amdgcn_mfma_f32_16x16x32_bf16(a_h, b_l, d, 0, 0, 0);
                d = __builtin_amdgcn_mfma_f32_16x16x32_bf16(a_l, b_h, d, 0, 0, 0);
            }
        }

        // ---- wait: this wave's 64 producers must have flagged step s ----
        if (s) {
            for (;;) {
                int v = __hip_atomic_load(fp, __ATOMIC_RELAXED,
                                          __HIP_MEMORY_SCOPE_AGENT);
                if (__all(v >= s)) break;
                __builtin_amdgcn_s_sleep(1);
            }
        }
        asm volatile("" ::: "memory");

        // ---- h-phase: y[s-1] loads + split + MFMA (skip at s==0: h==0) ----
        if (s) {
            const float* hprev = ybase + ((size_t)(s - 1) << 15);   // H_*B_
#pragma unroll
            for (int kt = 0; kt < 8; ++kt) {
                const int k0 = kh * 256 + kt * 32;
                float hv[8];
#pragma unroll
                for (int j = 0; j < 8; ++j)
                    hv[j] = hprev[((size_t)(k0 + ko[j]) << 6) + bcol];
                bf16x8 b_h, b_l;
#pragma unroll
                for (int j = 0; j < 8; ++j) {
                    unsigned u32 = __float_as_uint(hv[j]);
                    b_h[j] = (short)(u32 >> 16);
                    float hi_f = __uint_as_float(u32 & 0xffff0000u);
                    b_l[j] = (short)(__float_as_uint(hv[j] - hi_f) >> 16);
                }
                bf16x8 a_h = hA[((kh * 8 + kt) * 2 + 0) * 64 + lane];
                bf16x8 a_l = hA[((kh * 8 + kt) * 2 + 1) * 64 + lane];
                d = __builtin_amdgcn_mfma_f32_16x16x32_bf16(a_h, b_h, d, 0, 0, 0);
                d = __builtin_amdgcn_mfma_f32_16x16x32_bf16(a_h, b_l, d, 0, 0, 0);
                d = __builtin_amdgcn_mfma_f32_16x16x32_bf16(a_l, b_h, d, 0, 0, 0);
            }
        }

        // ---- dump D (C/D layout: col=lane&15, row=(lane>>4)*4+reg) ----
        {
            const int m0 = (lane >> 4) << 2;
#pragma unroll
            for (int r = 0; r < 4; ++r)
                parts[(kh * 16 + m0 + r) * 66 + bcol] = d[r];
        }
        __syncthreads();

        if (wq < 4) {
            const int rb = wq << 2;   // m = uu*4 + g, uu = wq
            float g0 = bi0 + parts[(rb + 0) * 66 + lane] + parts[(16 + rb + 0) * 66 + lane];
            float g1 = bi1 + parts[(rb + 1) * 66 + lane] + parts[(16 + rb + 1) * 66 + lane];
            float g2 = bi2 + parts[(rb + 2) * 66 + lane] + parts[(16 + rb + 2) * 66 + lane];
            float g3 = bi3 + parts[(rb + 3) * 66 + lane] + parts[(16 + rb + 3) * 66 + lane];
            float ii = 1.f / (1.f + expf(-g0));
            float ff = 1.f / (1.f + expf(-g1));
            float gg = tanhf(g2);
            float oo = 1.f / (1.f + expf(-g3));
            float cn2 = ff * c_reg + ii * gg;
            float hn = oo * tanhf(cn2);
            c_reg = cn2;                       // post-length state is don't-care
            float yv = (s < Lb) ? hn : 0.f;
            __hip_atomic_store(&ybase[((size_t)(s * H_ + uF) << 6) + lane], yv,
                               __ATOMIC_RELAXED, __HIP_MEMORY_SCOPE_AGENT);
        }

        // drain y stores, block barrier, one flag store (no RMW).
        asm volatile("s_waitcnt vmcnt(0)" ::: "memory");
        __syncthreads();
        if (tid == 0)
            __hip_atomic_store(myflag, s + 1, __ATOMIC_RELAXED,
                               __HIP_MEMORY_SCOPE_AGENT);
    }
}

// ---------------- logits / CRF epilogue (unchanged, verified) ----------------
__global__ __launch_bounds__(256) void k_logits(const float* __restrict__ yf,
                                                const float* __restrict__ ybr,
                                                const float* __restrict__ wc,
                                                const float* __restrict__ bcv,
                                                float* __restrict__ L1,
                                                float* __restrict__ L2p) {
    __shared__ float smem[T_ * H_];
    int part = blockIdx.x >> 9;
    int s = blockIdx.x & 511;
    int tid = threadIdx.x;
    const float* y = part ? ybr : yf;
    float* Ldst = part ? L2p : L1;
    for (int idx = tid; idx < T_ * H_; idx += 256) {
        int t = idx >> 9;
        int h = idx & 511;
        smem[idx] = wc[(size_t)t * 1024 + part * 512 + h];
    }
    __syncthreads();
    int q = tid >> 6, b = tid & 63;
    float acc[T_];
#pragma unroll
    for (int t = 0; t < T_; ++t) acc[t] = 0.f;
    const float* yrow = y + (size_t)s * H_ * B_ + b;
    for (int h = q * 128; h < q * 128 + 128; ++h) {
        float a = yrow[(size_t)h * B_];
#pragma unroll
        for (int t = 0; t < T_; ++t) acc[t] += a * smem[t * H_ + h];
    }
    __syncthreads();
    float* pl = smem;
#pragma unroll
    for (int t = 0; t < T_; ++t) pl[(q * 64 + b) * 26 + t] = acc[t];
    __syncthreads();
    for (int idx = tid; idx < B_ * T_; idx += 256) {
        int bb2 = idx / T_;
        int t = idx - bb2 * T_;
        float v = pl[(0 * 64 + bb2) * 26 + t] + pl[(1 * 64 + bb2) * 26 + t] +
                  pl[(2 * 64 + bb2) * 26 + t] + pl[(3 * 64 + bb2) * 26 + t];
        if (!part) v += bcv[t];
        Ldst[((size_t)bb2 * S_ + s) * T_ + t] = v;
    }
}

__global__ void k_combine(const float* __restrict__ L1, const float* __restrict__ L2p,
                          const int* __restrict__ len, float* __restrict__ outlog) {
    int id = blockIdx.x * 256 + threadIdx.x;  // 32768 = B*S
    int b = id >> 9;
    int s = id & 511;
    int L = len[b];
    int sr = (s < L) ? (L - 1 - s) : s;
    const float* p1 = L1 + ((size_t)b * S_ + s) * T_;
    const float* p2 = L2p + ((size_t)b * S_ + sr) * T_;
    float* o = outlog + ((size_t)b * S_ + s) * T_;
#pragma unroll
    for (int t = 0; t < T_; ++t) o[t] = p1[t] + p2[t];
}

__global__ __launch_bounds__(64) void k_crf_nll(const float* __restrict__ em,
                                                const int* __restrict__ labels,
                                                const int* __restrict__ len,
                                                const float* __restrict__ cs,
                                                const float* __restrict__ ce,
                                                const float* __restrict__ ctr,
                                                float* __restrict__ llh) {
    int b = blockIdx.x, tid = threadIdx.x;
    __shared__ float tr[T_ * T_];
    __shared__ float sa[T_], sb[T_];
    for (int idx = tid; idx < T_ * T_; idx += 64) tr[idx] = ctr[idx];
    const float* e = em + (size_t)b * S_ * T_;
    int L = len[b];
    if (tid < T_) sa[tid] = cs[tid] + e[tid];
    __syncthreads();
    float* cur = sa;
    float* nx = sb;
    for (int t = 1; t < L; ++t) {
        if (tid < T_) {
            float m = -1e30f;
            for (int i = 0; i < T_; ++i) m = fmaxf(m, cur[i] + tr[i * T_ + tid]);
            float ssum = 0.f;
            for (int i = 0; i < T_; ++i) ssum += expf(cur[i] + tr[i * T_ + tid] - m);
            nx[tid] = m + logf(ssum) + e[(size_t)t * T_ + tid];
        }
        __syncthreads();
        float* tmp = cur; cur = nx; nx = tmp;
    }
    float part = 0.f;
    for (int t = tid; t < S_; t += 64) {
        if (t >= 1 && t < L) {
            int lp = labels[b * S_ + t - 1];
            int lc = labels[b * S_ + t];
            part += tr[lp * T_ + lc] + e[(size_t)t * T_ + lc];
        }
    }
    for (int off = 32; off; off >>= 1) part += __shfl_down(part, off, 64);
    if (tid == 0) {
        float m = -1e30f;
        for (int j = 0; j < T_; ++j) m = fmaxf(m, cur[j] + ce[j]);
        float ssum = 0.f;
        for (int j = 0; j < T_; ++j) ssum += expf(cur[j] + ce[j] - m);
        float denom = m + logf(ssum);
        int l0 = labels[b * S_];
        int lL = labels[b * S_ + L - 1];
        float num = cs[l0] + e[l0] + part + ce[lL];
        llh[b] = num - denom;
    }
}

__global__ void k_loss(const float* __restrict__ llh, const int* __restrict__ len,
                       float* __restrict__ out0) {
    int tid = threadIdx.x;
    float v = llh[tid];
    float n = (float)len[tid];
    for (int off = 32; off; off >>= 1) {
        v += __shfl_down(v, off, 64);
        n += __shfl_down(n, off, 64);
    }
    if (tid == 0) out0[0] = -(v / n);
}

__global__ __launch_bounds__(64) void k_viterbi(const float* __restrict__ em,
                                                const int* __restrict__ len,
                                                const float* __restrict__ cs,
                                                const float* __restrict__ ce,
                                                const float* __restrict__ ctr,
                                                float* __restrict__ otags,
                                                float* __restrict__ omask) {
    int b = blockIdx.x, tid = threadIdx.x;
    __shared__ float tr[T_ * T_];
    __shared__ float sa[T_], sb[T_];
    __shared__ unsigned char hist[(S_ - 1) * T_];
    __shared__ unsigned char tg[S_];
    for (int idx = tid; idx < T_ * T_; idx += 64) tr[idx] = ctr[idx];
    const float* e = em + (size_t)b * S_ * T_;
    int L = len[b];
    if (tid < T_) sa[tid] = cs[tid] + e[tid];
    __syncthreads();
    float* cur = sa;
    float* nx = sb;
    for (int t = 1; t < L; ++t) {
        if (tid < T_) {
            float best = -1e30f;
            int bi = 0;
            for (int i = 0; i < T_; ++i) {
                float v = cur[i] + tr[i * T_ + tid];
                if (v > best) { best = v; bi = i; }
            }
            nx[tid] = best + e[(size_t)t * T_ + tid];
            hist[(t - 1) * T_ + tid] = (unsigned char)bi;
        }
        __syncthreads();
        float* tmp = cur; cur = nx; nx = tmp;
    }
    if (tid == 0) {
        float best = -1e30f;
        int bt = 0;
        for (int j = 0; j < T_; ++j) {
            float v = cur[j] + ce[j];
            if (v > best) { best = v; bt = j; }
        }
        tg[S_ - 1] = (unsigned char)bt;
        for (int t = S_ - 2; t >= 0; --t) {
            if (t + 1 < L) bt = hist[t * T_ + bt];
            tg[t] = (unsigned char)bt;
        }
    }
    __syncthreads();
    for (int idx = tid; idx < S_; idx += 64) {
        otags[(size_t)b * S_ + idx] = (float)tg[idx];
        omask[(size_t)b * S_ + idx] = (idx < L) ? 1.f : 0.f;
    }
}

// ---------------- host launch ----------------
extern "C" void kernel_launch(void* const* d_in, const int* in_sizes, int n_in,
                              void* d_out, int out_size, void* d_ws, size_t ws_size,
                              hipStream_t stream) {
    const float* x    = (const float*)d_in[0];
    const float* wihf = (const float*)d_in[1];
    const float* whhf = (const float*)d_in[2];
    const float* bf   = (const float*)d_in[3];
    const float* wihb = (const float*)d_in[4];
    const float* whhb = (const float*)d_in[5];
    const float* bb   = (const float*)d_in[6];
    const float* wc   = (const float*)d_in[7];
    const float* bc   = (const float*)d_in[8];
    const float* cs   = (const float*)d_in[9];
    const float* ce   = (const float*)d_in[10];
    const float* ctr  = (const float*)d_in[11];
    const int* am     = (const int*)d_in[12];
    const int* labels = (const int*)d_in[13];

    float* ws   = (float*)d_ws;
    short* xbfr = (short*)(ws + OFS_XBF);
    short* whfr = (short*)(ws + OFS_WHF);
    short* wxfr = (short*)(ws + OFS_WXF);
    float* yf   = ws + OFS_YF;
    float* ybr  = ws + OFS_YB;
    float* L1p  = ws + OFS_L1;
    float* L2p  = ws + OFS_L2;
    int*   lenp = (int*)(ws + OFS_LEN);
    float* llhp = ws + OFS_LLH;
    int*   flgp = (int*)(ws + OFS_FLG);
    float* out  = (float*)d_out;

    k_lengths<<<1, 64, 0, stream>>>(am, lenp);
    k_prep_hfrag<<<2048, 256, 0, stream>>>(whhf, whhb, whfr);
    k_prep_xfrag<<<2048, 256, 0, stream>>>(wihf, wihb, wxfr);
    k_prep_xb<<<8192, 256, 0, stream>>>(x, lenp, xbfr);
    k_zero<<<16, 256, 0, stream>>>(ws + OFS_FLG, 2 * 128 * 16);  // flags

    {
        void* kargs[] = {
            (void*)&whfr, (void*)&wxfr, (void*)&xbfr,
            (void*)&yf, (void*)&ybr,
            (void*)&bf, (void*)&bb,
            (void*)&lenp, (void*)&flgp
        };
        hipLaunchCooperativeKernel((const void*)k_scan,
                                   dim3(256), dim3(512), kargs, 0, stream);
    }

    k_logits<<<1024, 256, 0, stream>>>(yf, ybr, wc, bc, L1p, L2p);
    k_combine<<<128, 256, 0, stream>>>(L1p, L2p, lenp, out + OFF_LOGITS);
    k_crf_nll<<<64, 64, 0, stream>>>(out + OFF_LOGITS, labels, lenp, cs, ce, ctr, llhp);
    k_loss<<<1, 64, 0, stream>>>(llhp, lenp, out);
    k_viterbi<<<64, 64, 0, stream>>>(out + OFF_LOGITS, lenp, cs, ce, ctr,
                                     out + OFF_TAGS, out + OFF_MASK);
}